// Round 9
// baseline (195.474 us; speedup 1.0000x reference)
//
#include <hip/hip_runtime.h>
#include <hip/hip_bf16.h>

typedef _Float16 half8 __attribute__((ext_vector_type(8)));
typedef _Float16 half4v __attribute__((ext_vector_type(4)));
typedef _Float16 half2 __attribute__((ext_vector_type(2)));
typedef float f32x4 __attribute__((ext_vector_type(4)));

constexpr int NT = 4096;   // tokens
constexpr int CH = 1024;   // channels
constexpr int NH = 16;     // heads
constexpr int HD = 64;     // head dim
constexpr int C3 = 3072;   // 3*CH

#if __has_builtin(__builtin_amdgcn_exp2f)
#define EXP2(x) __builtin_amdgcn_exp2f(x)
#else
#define EXP2(x) exp2f(x)
#endif

#define GLOAD_LDS16(gp, lp) __builtin_amdgcn_global_load_lds( \
    (const __attribute__((address_space(1))) void*)(gp),      \
    (__attribute__((address_space(3))) void*)(lp), 16, 0, 0)

static __device__ inline half2 pk_f16(float a, float b) {
  auto r = __builtin_amdgcn_cvt_pkrtz(a, b);   // v_cvt_pkrtz_f16_f32
  return *(half2*)&r;
}

// ---------------- f32 -> f16 convert ----------------
__global__ __launch_bounds__(256) void cvt_kernel(const float* __restrict__ in,
                                                  _Float16* __restrict__ out, int n4) {
  int i = blockIdx.x * 256 + threadIdx.x;
  if (i >= n4) return;
  float4 v = ((const float4*)in)[i];
  half4v h;
  h[0] = (_Float16)v.x; h[1] = (_Float16)v.y; h[2] = (_Float16)v.z; h[3] = (_Float16)v.w;
  ((half4v*)out)[i] = h;
}

// ---------------- GEMM: C[M][Nn] = A[M][K] * Bt[Nn][K]^T ----------------
// m97 structure: 128x128 tile, BK=32, linear LDS, global_load_lds width-16.
template <typename OutT>
__global__ __launch_bounds__(256) void gemm_bt(const _Float16* __restrict__ A,
                                               const _Float16* __restrict__ Bt,
                                               OutT* __restrict__ Cc,
                                               int M, int Nn, int K) {
  __shared__ _Float16 As[128][32];
  __shared__ _Float16 Bs[128][32];
  const int tid = threadIdx.x;
  const int lane = tid & 63, w = tid >> 6;
  const int l15 = lane & 15, l4 = lane >> 4;
  const int m0 = blockIdx.x * 128, n0 = blockIdx.y * 128;
  const int wr = w >> 1, wc = w & 1;
  const int rb = w * 32;           // wave's 32-row staging band
  const int rl = lane >> 2;        // row within 16-row chunk (4 lanes/row)
  const int cb = (lane & 3) * 8;   // f16 col of this lane's 16B
  f32x4 acc[4][4] = {};
  for (int k0 = 0; k0 < K; k0 += 32) {
    __syncthreads();               // prior-tile reads done
    GLOAD_LDS16(A  + (size_t)(m0 + rb + rl) * K + k0 + cb,      &As[rb][0]);
    GLOAD_LDS16(A  + (size_t)(m0 + rb + 16 + rl) * K + k0 + cb, &As[rb + 16][0]);
    GLOAD_LDS16(Bt + (size_t)(n0 + rb + rl) * K + k0 + cb,      &Bs[rb][0]);
    GLOAD_LDS16(Bt + (size_t)(n0 + rb + 16 + rl) * K + k0 + cb, &Bs[rb + 16][0]);
    __syncthreads();               // vmcnt(0) drain before barrier
    half8 af[4], bf[4];
#pragma unroll
    for (int mt = 0; mt < 4; ++mt) af[mt] = *(half8*)&As[wr * 64 + mt * 16 + l15][l4 * 8];
#pragma unroll
    for (int nt = 0; nt < 4; ++nt) bf[nt] = *(half8*)&Bs[wc * 64 + nt * 16 + l15][l4 * 8];
#pragma unroll
    for (int mt = 0; mt < 4; ++mt)
#pragma unroll
      for (int nt = 0; nt < 4; ++nt)
        acc[mt][nt] = __builtin_amdgcn_mfma_f32_16x16x32_f16(af[mt], bf[nt], acc[mt][nt], 0, 0, 0);
  }
#pragma unroll
  for (int mt = 0; mt < 4; ++mt)
#pragma unroll
    for (int nt = 0; nt < 4; ++nt)
#pragma unroll
      for (int r = 0; r < 4; ++r) {
        int row = m0 + wr * 64 + mt * 16 + l4 * 4 + r;
        int col = n0 + wc * 64 + nt * 16 + l15;
        Cc[(size_t)row * Nn + col] = (OutT)acc[mt][nt][r];
      }
}

// ---------------- fused RMSNorm + RoPE for Q,K ----------------
// one wave per (n, h); lane = d. Q row-major pre-scaled by 0.125*log2(e).
// K written into fragment-swizzled KF layout (see attn_kernel header).
__global__ __launch_bounds__(256) void rmsrope_kernel(const _Float16* __restrict__ qkv,
                                                      const int* __restrict__ coords,
                                                      const float* __restrict__ gq,
                                                      const float* __restrict__ gk,
                                                      _Float16* __restrict__ Qh,
                                                      _Float16* __restrict__ KF) {
  int gw = blockIdx.x * 4 + (threadIdx.x >> 6);
  int lane = threadIdx.x & 63;
  int n = gw >> 4, h = gw & 15;
  float q = (float)qkv[(size_t)n * C3 + h * HD + lane];
  float k = (float)qkv[(size_t)n * C3 + CH + h * HD + lane];
  float sq = q * q, sk = k * k;
#pragma unroll
  for (int m = 1; m < 64; m <<= 1) { sq += __shfl_xor(sq, m); sk += __shfl_xor(sk, m); }
  q *= 8.0f / fmaxf(sqrtf(sq), 1e-12f) * gq[h * HD + lane];
  k *= 8.0f / fmaxf(sqrtf(sk), 1e-12f) * gk[h * HD + lane];
  int j = lane >> 1, p = j >> 3, dr = j & 7;
  // freq = 10000^(-dr/64) = exp(-dr * ln(1e4)/64)
  float ang = (float)coords[n * 5 + 1 + p] * __expf(-(float)dr * 0.14391157f);
  float cs = cosf(ang), sn = sinf(ang);
  float qp = __shfl_xor(q, 1), kp = __shfl_xor(k, 1);
  float qr, kr;
  if ((lane & 1) == 0) { qr = q * cs - qp * sn; kr = k * cs - kp * sn; }
  else                 { qr = qp * sn + q * cs; kr = kp * sn + k * cs; }
  Qh[((size_t)h * NT + n) * HD + lane] = (_Float16)(qr * 0.18033688f);  // 0.125*log2e
  // KF fragment-swizzle: key m=n&63 -> (t, i15); d=lane -> (kk, l4, j)
  int m64 = n & 63, kb = n >> 6;
  int t   = 2 * (m64 >> 5) + ((m64 >> 2) & 1);
  int i15 = 4 * ((m64 >> 3) & 3) + (m64 & 3);
  int kk = lane >> 5, ll4 = (lane >> 3) & 3, jj = lane & 7;
  KF[(size_t)h * NT * HD + (size_t)kb * 4096 +
     (size_t)(((t * 2 + kk) * 64 + ll4 * 16 + i15) * 8 + jj)] = (_Float16)kr;
}

// ---------------- V into fragment-swizzled VF layout ----------------
// VF element (kb, f=t*2+kk, lane=l4*16+l15, j) = V[key=kb*64+kk*32+l4*8+j][d=t*16+l15]
__global__ __launch_bounds__(256) void vtrans_kernel(const _Float16* __restrict__ qkv,
                                                     _Float16* __restrict__ VF) {
  __shared__ _Float16 L[64][72];
  int h = blockIdx.y, n0 = blockIdx.x * 64, kb = blockIdx.x, t0 = threadIdx.x;
#pragma unroll
  for (int i = 0; i < 2; ++i) {
    int cid = t0 + i * 256, r = cid >> 3, c = cid & 7;
    *(half8*)&L[r][c * 8] = *(const half8*)(qkv + (size_t)(n0 + r) * C3 + 2 * CH + h * HD + c * 8);
  }
  __syncthreads();
#pragma unroll
  for (int i = 0; i < 2; ++i) {
    int cid = t0 + i * 256, d = cid >> 3, c = cid & 7;
    half8 v;
#pragma unroll
    for (int jj = 0; jj < 8; ++jj) v[jj] = L[c * 8 + jj][d];
    size_t flat = (size_t)h * NT * HD + (size_t)kb * 4096 +
                  (size_t)((((d >> 4) * 2 + (c >> 2)) * 64 + (c & 3) * 16 + (d & 15)) * 8);
    *(half8*)(VF + flat) = v;
  }
}

// ---------------- flash attention: 3-buffer gload_lds pipeline ----------------
// one block = (head, 128-row Q tile); 4 waves, 32 q-rows each.
// Bounded scores (|S|<=8) -> no max tracking. Swapped QK^T -> P in registers.
// K/V staged from frag-swizzled HBM layouts via global_load_lds (linear dest,
// loads tracked in vmcnt -> compiler cannot sink them; one barrier per tile,
// 3-buffer rotation removes the write-after-read hazard).
// Cross-tile sv pipeline: qk(kb) MFMAs are independent of softmax(kb-1) VALU
// -> scheduler interleaves both pipes. lsum via MFMA ones-frag.
__global__ __launch_bounds__(256, 2) void attn_kernel(const _Float16* __restrict__ Qh,
                                                      const _Float16* __restrict__ KF,
                                                      const _Float16* __restrict__ VF,
                                                      _Float16* __restrict__ Oh) {
  __shared__ _Float16 KB[3][4096];
  __shared__ _Float16 VB[3][4096];
  const int tid = threadIdx.x, lane = tid & 63, w = tid >> 6;
  const int l15 = lane & 15, l4 = lane >> 4;
  // XCD-aware mapping: 512 blocks, heads {2x,2x+1} pinned to XCD x
  int bid = blockIdx.x;
  int s = bid >> 3;                 // [0,64)
  int h = (bid & 7) * 2 + (s >> 5);
  int n0 = (s & 31) * 128;
  half8 qf[2][2];  // [qb][kk], q rows = n0 + w*32 + qb*16 + l15
#pragma unroll
  for (int qb = 0; qb < 2; ++qb)
#pragma unroll
    for (int kk = 0; kk < 2; ++kk)
      qf[qb][kk] = *(const half8*)(Qh + ((size_t)h * NT + n0 + w * 32 + qb * 16 + l15) * HD + kk * 32 + l4 * 8);
  f32x4 acc[2][4] = {};
  f32x4 acc5[2] = {};              // lsum accumulators (col 0 = row-sum)
  half8 of1 = {};                  // ones B-frag: B[idx=0][k]=1 -> l15==0 lanes
  if (l15 == 0) {
#pragma unroll
    for (int jq = 0; jq < 8; ++jq) of1[jq] = (_Float16)1.0f;
  }
  const _Float16* KFh = KF + (size_t)h * NT * HD;
  const _Float16* VFh = VF + (size_t)h * NT * HD;
  // stage tile kb into buffer b: 4 x block-wide gload (K c0,c1 + V c0,c1)
  auto stage = [&](int kb, int b) {
    size_t g0 = (size_t)kb * 4096 + w * 512 + lane * 8;
#pragma unroll
    for (int cch = 0; cch < 2; ++cch) {
      GLOAD_LDS16(KFh + g0 + cch * 2048, &KB[b][cch * 2048 + w * 512]);
      GLOAD_LDS16(VFh + g0 + cch * 2048, &VB[b][cch * 2048 + w * 512]);
    }
  };
  auto qk = [&](int b, f32x4 (&sv)[2][4]) {
    half8 kf[8];
#pragma unroll
    for (int f = 0; f < 8; ++f) kf[f] = *(half8*)&KB[b][f * 512 + lane * 8];
#pragma unroll
    for (int t = 0; t < 4; ++t)
#pragma unroll
      for (int kk = 0; kk < 2; ++kk) {
        sv[0][t] = __builtin_amdgcn_mfma_f32_16x16x32_f16(kf[t * 2 + kk], qf[0][kk], sv[0][t], 0, 0, 0);
        sv[1][t] = __builtin_amdgcn_mfma_f32_16x16x32_f16(kf[t * 2 + kk], qf[1][kk], sv[1][t], 0, 0, 0);
      }
  };
  union U { half8 v; half2 p[4]; };
  auto sm = [&](f32x4 (&sv)[2][4], U (&u)[2][2]) {
#pragma unroll
    for (int qb = 0; qb < 2; ++qb) {
      float e[4][4];
#pragma unroll
      for (int t = 0; t < 4; ++t)
#pragma unroll
        for (int r = 0; r < 4; ++r) e[t][r] = EXP2(sv[qb][t][r]);
      u[qb][0].p[0] = pk_f16(e[0][0], e[0][1]); u[qb][0].p[1] = pk_f16(e[0][2], e[0][3]);
      u[qb][0].p[2] = pk_f16(e[1][0], e[1][1]); u[qb][0].p[3] = pk_f16(e[1][2], e[1][3]);
      u[qb][1].p[0] = pk_f16(e[2][0], e[2][1]); u[qb][1].p[1] = pk_f16(e[2][2], e[2][3]);
      u[qb][1].p[2] = pk_f16(e[3][0], e[3][1]); u[qb][1].p[3] = pk_f16(e[3][2], e[3][3]);
    }
  };
  auto pv = [&](int b, U (&u)[2][2]) {
    half8 vf[8];
#pragma unroll
    for (int f = 0; f < 8; ++f) vf[f] = *(half8*)&VB[b][f * 512 + lane * 8];
#pragma unroll
    for (int t = 0; t < 4; ++t)
#pragma unroll
      for (int kk = 0; kk < 2; ++kk) {
        acc[0][t] = __builtin_amdgcn_mfma_f32_16x16x32_f16(u[0][kk].v, vf[t * 2 + kk], acc[0][t], 0, 0, 0);
        acc[1][t] = __builtin_amdgcn_mfma_f32_16x16x32_f16(u[1][kk].v, vf[t * 2 + kk], acc[1][t], 0, 0, 0);
      }
    acc5[0] = __builtin_amdgcn_mfma_f32_16x16x32_f16(u[0][0].v, of1, acc5[0], 0, 0, 0);
    acc5[0] = __builtin_amdgcn_mfma_f32_16x16x32_f16(u[0][1].v, of1, acc5[0], 0, 0, 0);
    acc5[1] = __builtin_amdgcn_mfma_f32_16x16x32_f16(u[1][0].v, of1, acc5[1], 0, 0, 0);
    acc5[1] = __builtin_amdgcn_mfma_f32_16x16x32_f16(u[1][1].v, of1, acc5[1], 0, 0, 0);
  };
  f32x4 svA[2][4] = {}, svB[2][4] = {};
  U uA[2][2], uB[2][2];
  stage(0, 0);
  __syncthreads();                 // tile 0 staged
  stage(1, 1);                     // in flight during qk(0)
  qk(0, svA);
  for (int kb = 1; kb < 64; ++kb) {
    int bc = kb % 3, bp = (kb - 1) % 3, bn = (kb + 1) % 3;
    __syncthreads();               // stage(kb) done; all reads of buffer bn done
    if (kb + 1 < 64) stage(kb + 1, bn);
    if (kb & 1) {
      qk(bc, svB); sm(svA, uA); pv(bp, uA);
#pragma unroll
      for (int qb = 0; qb < 2; ++qb)
#pragma unroll
        for (int t = 0; t < 4; ++t) svA[qb][t] = (f32x4){0.f, 0.f, 0.f, 0.f};
    } else {
      qk(bc, svA); sm(svB, uB); pv(bp, uB);
#pragma unroll
      for (int qb = 0; qb < 2; ++qb)
#pragma unroll
        for (int t = 0; t < 4; ++t) svB[qb][t] = (f32x4){0.f, 0.f, 0.f, 0.f};
    }
  }
  // epilogue: tile 63 (odd -> svB), buffer 63%3 == 0
  sm(svB, uB); pv(0, uB);
  // lsum for q-row (qb*16 + l4*4+r) sits in acc5[qb][r] of lane (l4, l15=0)
#pragma unroll
  for (int qb = 0; qb < 2; ++qb) {
    float linv[4];
#pragma unroll
    for (int r = 0; r < 4; ++r) linv[r] = 1.0f / __shfl(acc5[qb][r], lane & 48);
#pragma unroll
    for (int t = 0; t < 4; ++t)
#pragma unroll
      for (int r = 0; r < 4; ++r) {
        int row = n0 + w * 32 + qb * 16 + l4 * 4 + r;
        Oh[(size_t)row * CH + h * HD + t * 16 + l15] = (_Float16)(acc[qb][t][r] * linv[r]);
      }
  }
}

extern "C" void kernel_launch(void* const* d_in, const int* in_sizes, int n_in,
                              void* d_out, int out_size, void* d_ws, size_t ws_size,
                              hipStream_t stream) {
  const float* x      = (const float*)d_in[0];
  const int*   coords = (const int*)d_in[1];
  const float* w_qkv  = (const float*)d_in[2];
  const float* w_out  = (const float*)d_in[3];
  const float* gq     = (const float*)d_in[4];
  const float* gk     = (const float*)d_in[5];
  float* out = (float*)d_out;

  char* ws = (char*)d_ws;
  size_t off = 0;
  auto alloc = [&](size_t bytes) { char* p = ws + off; off += bytes; return p; };
  _Float16* xh   = (_Float16*)alloc((size_t)NT * CH * 2);  // x in f16
  _Float16* wqh  = (_Float16*)alloc((size_t)C3 * CH * 2);  // w_qkv f16
  _Float16* woh  = (_Float16*)alloc((size_t)CH * CH * 2);  // w_out f16
  _Float16* qkvh = (_Float16*)alloc((size_t)NT * C3 * 2);  // qkv f16
  _Float16* Qh   = (_Float16*)alloc((size_t)NT * CH * 2);  // [H][N][64], pre-scaled
  _Float16* KFh  = (_Float16*)alloc((size_t)NT * CH * 2);  // frag-swizzled K
  _Float16* VFh  = (_Float16*)alloc((size_t)NT * CH * 2);  // frag-swizzled V
  _Float16* Oh   = (_Float16*)alloc((size_t)NT * CH * 2);  // attn out [N][C]
  if (off > ws_size) return;  // workspace too small: fail cleanly

  cvt_kernel<<<NT * CH / 4 / 256, 256, 0, stream>>>(x, xh, NT * CH / 4);
  cvt_kernel<<<C3 * CH / 4 / 256, 256, 0, stream>>>(w_qkv, wqh, C3 * CH / 4);
  cvt_kernel<<<CH * CH / 4 / 256, 256, 0, stream>>>(w_out, woh, CH * CH / 4);
  gemm_bt<_Float16><<<dim3(NT / 128, C3 / 128), 256, 0, stream>>>(xh, wqh, qkvh, NT, C3, CH);
  rmsrope_kernel<<<NT * NH / 4, 256, 0, stream>>>(qkvh, coords, gq, gk, Qh, KFh);
  vtrans_kernel<<<dim3(NT / 64, NH), 256, 0, stream>>>(qkvh, VFh);
  attn_kernel<<<NH * (NT / 128), 256, 0, stream>>>(Qh, KFh, VFh, Oh);
  gemm_bt<float><<<dim3(NT / 128, CH / 128), 256, 0, stream>>>(Oh, woh, out, NT, CH, CH);
}

// Round 10
// 178.890 us; speedup vs baseline: 1.0927x; 1.0927x over previous
//
#include <hip/hip_runtime.h>
#include <hip/hip_bf16.h>

typedef _Float16 half8 __attribute__((ext_vector_type(8)));
typedef _Float16 half4v __attribute__((ext_vector_type(4)));
typedef _Float16 half2 __attribute__((ext_vector_type(2)));
typedef float f32x4 __attribute__((ext_vector_type(4)));

constexpr int NT = 4096;   // tokens
constexpr int CH = 1024;   // channels
constexpr int NH = 16;     // heads
constexpr int HD = 64;     // head dim
constexpr int C3 = 3072;   // 3*CH

#if __has_builtin(__builtin_amdgcn_exp2f)
#define EXP2(x) __builtin_amdgcn_exp2f(x)
#else
#define EXP2(x) exp2f(x)
#endif

#define GLOAD_LDS16(gp, lp) __builtin_amdgcn_global_load_lds( \
    (const __attribute__((address_space(1))) void*)(gp),      \
    (__attribute__((address_space(3))) void*)(lp), 16, 0, 0)

static __device__ inline half2 pk_f16(float a, float b) {
  auto r = __builtin_amdgcn_cvt_pkrtz(a, b);   // v_cvt_pkrtz_f16_f32
  return *(half2*)&r;
}

// ---------------- f32 -> f16 convert ----------------
__global__ __launch_bounds__(256) void cvt_kernel(const float* __restrict__ in,
                                                  _Float16* __restrict__ out, int n4) {
  int i = blockIdx.x * 256 + threadIdx.x;
  if (i >= n4) return;
  float4 v = ((const float4*)in)[i];
  half4v h;
  h[0] = (_Float16)v.x; h[1] = (_Float16)v.y; h[2] = (_Float16)v.z; h[3] = (_Float16)v.w;
  ((half4v*)out)[i] = h;
}

// ---------------- GEMM: C[M][Nn] = A[M][K] * Bt[Nn][K]^T ----------------
// m97 structure: 128x128 tile, BK=32, linear LDS, global_load_lds width-16.
template <typename OutT>
__global__ __launch_bounds__(256) void gemm_bt(const _Float16* __restrict__ A,
                                               const _Float16* __restrict__ Bt,
                                               OutT* __restrict__ Cc,
                                               int M, int Nn, int K) {
  __shared__ _Float16 As[128][32];
  __shared__ _Float16 Bs[128][32];
  const int tid = threadIdx.x;
  const int lane = tid & 63, w = tid >> 6;
  const int l15 = lane & 15, l4 = lane >> 4;
  const int m0 = blockIdx.x * 128, n0 = blockIdx.y * 128;
  const int wr = w >> 1, wc = w & 1;
  const int rb = w * 32;           // wave's 32-row staging band
  const int rl = lane >> 2;        // row within 16-row chunk (4 lanes/row)
  const int cb = (lane & 3) * 8;   // f16 col of this lane's 16B
  f32x4 acc[4][4] = {};
  for (int k0 = 0; k0 < K; k0 += 32) {
    __syncthreads();               // prior-tile reads done
    GLOAD_LDS16(A  + (size_t)(m0 + rb + rl) * K + k0 + cb,      &As[rb][0]);
    GLOAD_LDS16(A  + (size_t)(m0 + rb + 16 + rl) * K + k0 + cb, &As[rb + 16][0]);
    GLOAD_LDS16(Bt + (size_t)(n0 + rb + rl) * K + k0 + cb,      &Bs[rb][0]);
    GLOAD_LDS16(Bt + (size_t)(n0 + rb + 16 + rl) * K + k0 + cb, &Bs[rb + 16][0]);
    __syncthreads();               // vmcnt(0) drain before barrier
    half8 af[4], bf[4];
#pragma unroll
    for (int mt = 0; mt < 4; ++mt) af[mt] = *(half8*)&As[wr * 64 + mt * 16 + l15][l4 * 8];
#pragma unroll
    for (int nt = 0; nt < 4; ++nt) bf[nt] = *(half8*)&Bs[wc * 64 + nt * 16 + l15][l4 * 8];
#pragma unroll
    for (int mt = 0; mt < 4; ++mt)
#pragma unroll
      for (int nt = 0; nt < 4; ++nt)
        acc[mt][nt] = __builtin_amdgcn_mfma_f32_16x16x32_f16(af[mt], bf[nt], acc[mt][nt], 0, 0, 0);
  }
#pragma unroll
  for (int mt = 0; mt < 4; ++mt)
#pragma unroll
    for (int nt = 0; nt < 4; ++nt)
#pragma unroll
      for (int r = 0; r < 4; ++r) {
        int row = m0 + wr * 64 + mt * 16 + l4 * 4 + r;
        int col = n0 + wc * 64 + nt * 16 + l15;
        Cc[(size_t)row * Nn + col] = (OutT)acc[mt][nt][r];
      }
}

// ---------------- fused RMSNorm + RoPE for Q,K ----------------
// one wave per (n, h); lane = d. Q row-major pre-scaled by 0.125*log2(e).
// K written into fragment-swizzled KF layout (see attn_kernel header).
__global__ __launch_bounds__(256) void rmsrope_kernel(const _Float16* __restrict__ qkv,
                                                      const int* __restrict__ coords,
                                                      const float* __restrict__ gq,
                                                      const float* __restrict__ gk,
                                                      _Float16* __restrict__ Qh,
                                                      _Float16* __restrict__ KF) {
  int gw = blockIdx.x * 4 + (threadIdx.x >> 6);
  int lane = threadIdx.x & 63;
  int n = gw >> 4, h = gw & 15;
  float q = (float)qkv[(size_t)n * C3 + h * HD + lane];
  float k = (float)qkv[(size_t)n * C3 + CH + h * HD + lane];
  float sq = q * q, sk = k * k;
#pragma unroll
  for (int m = 1; m < 64; m <<= 1) { sq += __shfl_xor(sq, m); sk += __shfl_xor(sk, m); }
  q *= 8.0f / fmaxf(sqrtf(sq), 1e-12f) * gq[h * HD + lane];
  k *= 8.0f / fmaxf(sqrtf(sk), 1e-12f) * gk[h * HD + lane];
  int j = lane >> 1, p = j >> 3, dr = j & 7;
  // freq = 10000^(-dr/64) = exp(-dr * ln(1e4)/64)
  float ang = (float)coords[n * 5 + 1 + p] * __expf(-(float)dr * 0.14391157f);
  float cs = cosf(ang), sn = sinf(ang);
  float qp = __shfl_xor(q, 1), kp = __shfl_xor(k, 1);
  float qr, kr;
  if ((lane & 1) == 0) { qr = q * cs - qp * sn; kr = k * cs - kp * sn; }
  else                 { qr = qp * sn + q * cs; kr = kp * sn + k * cs; }
  Qh[((size_t)h * NT + n) * HD + lane] = (_Float16)(qr * 0.18033688f);  // 0.125*log2e
  // KF fragment-swizzle: key m=n&63 -> (t, i15); d=lane -> (kk, l4, j)
  int m64 = n & 63, kb = n >> 6;
  int t   = 2 * (m64 >> 5) + ((m64 >> 2) & 1);
  int i15 = 4 * ((m64 >> 3) & 3) + (m64 & 3);
  int kk = lane >> 5, ll4 = (lane >> 3) & 3, jj = lane & 7;
  KF[(size_t)h * NT * HD + (size_t)kb * 4096 +
     (size_t)(((t * 2 + kk) * 64 + ll4 * 16 + i15) * 8 + jj)] = (_Float16)kr;
}

// ---------------- V into fragment-swizzled VF layout ----------------
// VF element (kb, f=t*2+kk, lane=l4*16+l15, j) = V[key=kb*64+kk*32+l4*8+j][d=t*16+l15]
__global__ __launch_bounds__(256) void vtrans_kernel(const _Float16* __restrict__ qkv,
                                                     _Float16* __restrict__ VF) {
  __shared__ _Float16 L[64][72];
  int h = blockIdx.y, n0 = blockIdx.x * 64, kb = blockIdx.x, t0 = threadIdx.x;
#pragma unroll
  for (int i = 0; i < 2; ++i) {
    int cid = t0 + i * 256, r = cid >> 3, c = cid & 7;
    *(half8*)&L[r][c * 8] = *(const half8*)(qkv + (size_t)(n0 + r) * C3 + 2 * CH + h * HD + c * 8);
  }
  __syncthreads();
#pragma unroll
  for (int i = 0; i < 2; ++i) {
    int cid = t0 + i * 256, d = cid >> 3, c = cid & 7;
    half8 v;
#pragma unroll
    for (int jj = 0; jj < 8; ++jj) v[jj] = L[c * 8 + jj][d];
    size_t flat = (size_t)h * NT * HD + (size_t)kb * 4096 +
                  (size_t)((((d >> 4) * 2 + (c >> 2)) * 64 + (c & 3) * 16 + (d & 15)) * 8);
    *(half8*)(VF + flat) = v;
  }
}

// ---------------- flash attention: single-buffer gload_lds (m97-style) ----------------
// one block = (head, 128-row Q tile); 4 waves, 32 q-rows each; grid 512
// (2 blocks/CU -> cross-block overlap covers the per-tile vmcnt drain, m114).
// Bounded scores (|S|<=8) -> no max tracking. Swapped QK^T -> P in registers.
// Staging: 4 block-wide global_load_lds from frag-swizzled KF/VF (linear dest,
// zero staging VALU / zero staging registers). barrier -> stage -> barrier.
// lsum via MFMA ones-frag.
__global__ __launch_bounds__(256, 2) void attn_kernel(const _Float16* __restrict__ Qh,
                                                      const _Float16* __restrict__ KF,
                                                      const _Float16* __restrict__ VF,
                                                      _Float16* __restrict__ Oh) {
  __shared__ _Float16 KB[4096];
  __shared__ _Float16 VB[4096];
  const int tid = threadIdx.x, lane = tid & 63, w = tid >> 6;
  const int l15 = lane & 15, l4 = lane >> 4;
  // XCD-aware mapping: 512 blocks, heads {2x,2x+1} pinned to XCD x
  int bid = blockIdx.x;
  int s = bid >> 3;                 // [0,64)
  int h = (bid & 7) * 2 + (s >> 5);
  int n0 = (s & 31) * 128;
  half8 qf[2][2];  // [qb][kk], q rows = n0 + w*32 + qb*16 + l15
#pragma unroll
  for (int qb = 0; qb < 2; ++qb)
#pragma unroll
    for (int kk = 0; kk < 2; ++kk)
      qf[qb][kk] = *(const half8*)(Qh + ((size_t)h * NT + n0 + w * 32 + qb * 16 + l15) * HD + kk * 32 + l4 * 8);
  f32x4 acc[2][4] = {};
  f32x4 acc5[2] = {};              // lsum accumulators (col 0 = row-sum)
  half8 of1 = {};                  // ones B-frag: B[idx=0][k]=1 -> l15==0 lanes
  if (l15 == 0) {
#pragma unroll
    for (int jq = 0; jq < 8; ++jq) of1[jq] = (_Float16)1.0f;
  }
  const _Float16* KFh = KF + (size_t)h * NT * HD + w * 512 + lane * 8;
  const _Float16* VFh = VF + (size_t)h * NT * HD + w * 512 + lane * 8;
  union U { half8 v; half2 p[4]; };
  for (int kb = 0; kb < 64; ++kb) {
    __syncthreads();               // prior-tile reads done
    {                              // stage tile kb (block-wide, linear dest)
      size_t g0 = (size_t)kb * 4096;
      GLOAD_LDS16(KFh + g0,        &KB[w * 512]);
      GLOAD_LDS16(KFh + g0 + 2048, &KB[2048 + w * 512]);
      GLOAD_LDS16(VFh + g0,        &VB[w * 512]);
      GLOAD_LDS16(VFh + g0 + 2048, &VB[2048 + w * 512]);
    }
    __syncthreads();               // vmcnt drain -> tile ready
    // QK^T (swapped): sv[qb][t], q = l15
    f32x4 sv[2][4] = {};
    __builtin_amdgcn_s_setprio(1);
#pragma unroll
    for (int t = 0; t < 4; ++t)
#pragma unroll
      for (int kk = 0; kk < 2; ++kk) {
        half8 kf = *(half8*)&KB[(t * 2 + kk) * 512 + lane * 8];
        sv[0][t] = __builtin_amdgcn_mfma_f32_16x16x32_f16(kf, qf[0][kk], sv[0][t], 0, 0, 0);
        sv[1][t] = __builtin_amdgcn_mfma_f32_16x16x32_f16(kf, qf[1][kk], sv[1][t], 0, 0, 0);
      }
    __builtin_amdgcn_s_setprio(0);
    // p = 2^S; pack with v_cvt_pkrtz. pf[kk][j] = e[2kk + (j>>2)][j&3]
    U u[2][2];
#pragma unroll
    for (int qb = 0; qb < 2; ++qb) {
      float e[4][4];
#pragma unroll
      for (int t = 0; t < 4; ++t)
#pragma unroll
        for (int r = 0; r < 4; ++r) e[t][r] = EXP2(sv[qb][t][r]);
      u[qb][0].p[0] = pk_f16(e[0][0], e[0][1]); u[qb][0].p[1] = pk_f16(e[0][2], e[0][3]);
      u[qb][0].p[2] = pk_f16(e[1][0], e[1][1]); u[qb][0].p[3] = pk_f16(e[1][2], e[1][3]);
      u[qb][1].p[0] = pk_f16(e[2][0], e[2][1]); u[qb][1].p[1] = pk_f16(e[2][2], e[2][3]);
      u[qb][1].p[2] = pk_f16(e[3][0], e[3][1]); u[qb][1].p[3] = pk_f16(e[3][2], e[3][3]);
    }
    // O += P @ V ; lsum via ones-frag (no LDS traffic)
    __builtin_amdgcn_s_setprio(1);
#pragma unroll
    for (int t = 0; t < 4; ++t)
#pragma unroll
      for (int kk = 0; kk < 2; ++kk) {
        half8 vf = *(half8*)&VB[(t * 2 + kk) * 512 + lane * 8];
        acc[0][t] = __builtin_amdgcn_mfma_f32_16x16x32_f16(u[0][kk].v, vf, acc[0][t], 0, 0, 0);
        acc[1][t] = __builtin_amdgcn_mfma_f32_16x16x32_f16(u[1][kk].v, vf, acc[1][t], 0, 0, 0);
      }
    acc5[0] = __builtin_amdgcn_mfma_f32_16x16x32_f16(u[0][0].v, of1, acc5[0], 0, 0, 0);
    acc5[0] = __builtin_amdgcn_mfma_f32_16x16x32_f16(u[0][1].v, of1, acc5[0], 0, 0, 0);
    acc5[1] = __builtin_amdgcn_mfma_f32_16x16x32_f16(u[1][0].v, of1, acc5[1], 0, 0, 0);
    acc5[1] = __builtin_amdgcn_mfma_f32_16x16x32_f16(u[1][1].v, of1, acc5[1], 0, 0, 0);
    __builtin_amdgcn_s_setprio(0);
  }
  // lsum for q-row (qb*16 + l4*4+r) sits in acc5[qb][r] of lane (l4, l15=0)
#pragma unroll
  for (int qb = 0; qb < 2; ++qb) {
    float linv[4];
#pragma unroll
    for (int r = 0; r < 4; ++r) linv[r] = 1.0f / __shfl(acc5[qb][r], lane & 48);
#pragma unroll
    for (int t = 0; t < 4; ++t)
#pragma unroll
      for (int r = 0; r < 4; ++r) {
        int row = n0 + w * 32 + qb * 16 + l4 * 4 + r;
        Oh[(size_t)row * CH + h * HD + t * 16 + l15] = (_Float16)(acc[qb][t][r] * linv[r]);
      }
  }
}

extern "C" void kernel_launch(void* const* d_in, const int* in_sizes, int n_in,
                              void* d_out, int out_size, void* d_ws, size_t ws_size,
                              hipStream_t stream) {
  const float* x      = (const float*)d_in[0];
  const int*   coords = (const int*)d_in[1];
  const float* w_qkv  = (const float*)d_in[2];
  const float* w_out  = (const float*)d_in[3];
  const float* gq     = (const float*)d_in[4];
  const float* gk     = (const float*)d_in[5];
  float* out = (float*)d_out;

  char* ws = (char*)d_ws;
  size_t off = 0;
  auto alloc = [&](size_t bytes) { char* p = ws + off; off += bytes; return p; };
  _Float16* xh   = (_Float16*)alloc((size_t)NT * CH * 2);  // x in f16
  _Float16* wqh  = (_Float16*)alloc((size_t)C3 * CH * 2);  // w_qkv f16
  _Float16* woh  = (_Float16*)alloc((size_t)CH * CH * 2);  // w_out f16
  _Float16* qkvh = (_Float16*)alloc((size_t)NT * C3 * 2);  // qkv f16
  _Float16* Qh   = (_Float16*)alloc((size_t)NT * CH * 2);  // [H][N][64], pre-scaled
  _Float16* KFh  = (_Float16*)alloc((size_t)NT * CH * 2);  // frag-swizzled K
  _Float16* VFh  = (_Float16*)alloc((size_t)NT * CH * 2);  // frag-swizzled V
  _Float16* Oh   = (_Float16*)alloc((size_t)NT * CH * 2);  // attn out [N][C]
  if (off > ws_size) return;  // workspace too small: fail cleanly

  cvt_kernel<<<NT * CH / 4 / 256, 256, 0, stream>>>(x, xh, NT * CH / 4);
  cvt_kernel<<<C3 * CH / 4 / 256, 256, 0, stream>>>(w_qkv, wqh, C3 * CH / 4);
  cvt_kernel<<<CH * CH / 4 / 256, 256, 0, stream>>>(w_out, woh, CH * CH / 4);
  gemm_bt<_Float16><<<dim3(NT / 128, C3 / 128), 256, 0, stream>>>(xh, wqh, qkvh, NT, C3, CH);
  rmsrope_kernel<<<NT * NH / 4, 256, 0, stream>>>(qkvh, coords, gq, gk, Qh, KFh);
  vtrans_kernel<<<dim3(NT / 64, NH), 256, 0, stream>>>(qkvh, VFh);
  attn_kernel<<<NH * (NT / 128), 256, 0, stream>>>(Qh, KFh, VFh, Oh);
  gemm_bt<float><<<dim3(NT / 128, CH / 128), 256, 0, stream>>>(Oh, woh, out, NT, CH, CH);
}

// Round 11
// 177.633 us; speedup vs baseline: 1.1004x; 1.0071x over previous
//
#include <hip/hip_runtime.h>
#include <hip/hip_bf16.h>

typedef _Float16 half8 __attribute__((ext_vector_type(8)));
typedef _Float16 half4v __attribute__((ext_vector_type(4)));
typedef _Float16 half2 __attribute__((ext_vector_type(2)));
typedef float f32x4 __attribute__((ext_vector_type(4)));

constexpr int NT = 4096;   // tokens
constexpr int CH = 1024;   // channels
constexpr int NH = 16;     // heads
constexpr int HD = 64;     // head dim
constexpr int C3 = 3072;   // 3*CH

#if __has_builtin(__builtin_amdgcn_exp2f)
#define EXP2(x) __builtin_amdgcn_exp2f(x)
#else
#define EXP2(x) exp2f(x)
#endif

#define GLOAD_LDS16(gp, lp) __builtin_amdgcn_global_load_lds( \
    (const __attribute__((address_space(1))) void*)(gp),      \
    (__attribute__((address_space(3))) void*)(lp), 16, 0, 0)

static __device__ inline half2 pk_f16(float a, float b) {
  auto r = __builtin_amdgcn_cvt_pkrtz(a, b);   // v_cvt_pkrtz_f16_f32
  return *(half2*)&r;
}

// ---------------- f32 -> f16 convert ----------------
__global__ __launch_bounds__(256) void cvt_kernel(const float* __restrict__ in,
                                                  _Float16* __restrict__ out, int n4) {
  int i = blockIdx.x * 256 + threadIdx.x;
  if (i >= n4) return;
  float4 v = ((const float4*)in)[i];
  half4v h;
  h[0] = (_Float16)v.x; h[1] = (_Float16)v.y; h[2] = (_Float16)v.z; h[3] = (_Float16)v.w;
  ((half4v*)out)[i] = h;
}

// ---------------- GEMM: C[M][Nn] = A[M][K] * Bt[Nn][K]^T ----------------
// 128x128 tile, BK=32, linear LDS, global_load_lds width-16 staging.
// 2-phase double-buffer: stage(next) issued BEFORE compute(current), one
// barrier per K-step -> load latency hides under MFMA, drain is ~free.
// Requires K % 64 == 0 (both call sites have K = 1024).
template <typename OutT>
__global__ __launch_bounds__(256) void gemm_bt(const _Float16* __restrict__ A,
                                               const _Float16* __restrict__ Bt,
                                               OutT* __restrict__ Cc,
                                               int M, int Nn, int K) {
  __shared__ _Float16 As[2][128][32];
  __shared__ _Float16 Bs[2][128][32];
  const int tid = threadIdx.x;
  const int lane = tid & 63, w = tid >> 6;
  const int l15 = lane & 15, l4 = lane >> 4;
  const int m0 = blockIdx.x * 128, n0 = blockIdx.y * 128;
  const int wr = w >> 1, wc = w & 1;
  const int rb = w * 32;           // wave's 32-row staging band
  const int rl = lane >> 2;        // row within 16-row chunk (4 lanes/row)
  const int cb = (lane & 3) * 8;   // f16 col of this lane's 16B
  f32x4 acc[4][4] = {};
  auto stage = [&](int k0, int buf) {
    GLOAD_LDS16(A  + (size_t)(m0 + rb + rl) * K + k0 + cb,      &As[buf][rb][0]);
    GLOAD_LDS16(A  + (size_t)(m0 + rb + 16 + rl) * K + k0 + cb, &As[buf][rb + 16][0]);
    GLOAD_LDS16(Bt + (size_t)(n0 + rb + rl) * K + k0 + cb,      &Bs[buf][rb][0]);
    GLOAD_LDS16(Bt + (size_t)(n0 + rb + 16 + rl) * K + k0 + cb, &Bs[buf][rb + 16][0]);
  };
  auto compute = [&](int buf) {
    half8 af[4], bf[4];
#pragma unroll
    for (int mt = 0; mt < 4; ++mt) af[mt] = *(half8*)&As[buf][wr * 64 + mt * 16 + l15][l4 * 8];
#pragma unroll
    for (int nt = 0; nt < 4; ++nt) bf[nt] = *(half8*)&Bs[buf][wc * 64 + nt * 16 + l15][l4 * 8];
#pragma unroll
    for (int mt = 0; mt < 4; ++mt)
#pragma unroll
      for (int nt = 0; nt < 4; ++nt)
        acc[mt][nt] = __builtin_amdgcn_mfma_f32_16x16x32_f16(af[mt], bf[nt], acc[mt][nt], 0, 0, 0);
  };
  stage(0, 0);
  __syncthreads();                 // tile 0 staged (vmcnt drain at barrier)
  for (int k0 = 0; k0 < K; k0 += 64) {
    stage(k0 + 32, 1);             // in flight during compute(0); k0+32 < K
    compute(0);
    __syncthreads();               // buf1 writes drained; buf0 readers done
    if (k0 + 64 < K) stage(k0 + 64, 0);
    compute(1);
    __syncthreads();
  }
#pragma unroll
  for (int mt = 0; mt < 4; ++mt)
#pragma unroll
    for (int nt = 0; nt < 4; ++nt)
#pragma unroll
      for (int r = 0; r < 4; ++r) {
        int row = m0 + wr * 64 + mt * 16 + l4 * 4 + r;
        int col = n0 + wc * 64 + nt * 16 + l15;
        Cc[(size_t)row * Nn + col] = (OutT)acc[mt][nt][r];
      }
}

// ---------------- fused RMSNorm + RoPE for Q,K ----------------
// one wave per (n, h); lane = d. Q row-major pre-scaled by 0.125*log2(e).
// K written into fragment-swizzled KF layout (see attn_kernel header).
__global__ __launch_bounds__(256) void rmsrope_kernel(const _Float16* __restrict__ qkv,
                                                      const int* __restrict__ coords,
                                                      const float* __restrict__ gq,
                                                      const float* __restrict__ gk,
                                                      _Float16* __restrict__ Qh,
                                                      _Float16* __restrict__ KF) {
  int gw = blockIdx.x * 4 + (threadIdx.x >> 6);
  int lane = threadIdx.x & 63;
  int n = gw >> 4, h = gw & 15;
  float q = (float)qkv[(size_t)n * C3 + h * HD + lane];
  float k = (float)qkv[(size_t)n * C3 + CH + h * HD + lane];
  float sq = q * q, sk = k * k;
#pragma unroll
  for (int m = 1; m < 64; m <<= 1) { sq += __shfl_xor(sq, m); sk += __shfl_xor(sk, m); }
  q *= 8.0f / fmaxf(sqrtf(sq), 1e-12f) * gq[h * HD + lane];
  k *= 8.0f / fmaxf(sqrtf(sk), 1e-12f) * gk[h * HD + lane];
  int j = lane >> 1, p = j >> 3, dr = j & 7;
  // freq = 10000^(-dr/64) = exp(-dr * ln(1e4)/64)
  float ang = (float)coords[n * 5 + 1 + p] * __expf(-(float)dr * 0.14391157f);
  float cs = cosf(ang), sn = sinf(ang);
  float qp = __shfl_xor(q, 1), kp = __shfl_xor(k, 1);
  float qr, kr;
  if ((lane & 1) == 0) { qr = q * cs - qp * sn; kr = k * cs - kp * sn; }
  else                 { qr = qp * sn + q * cs; kr = kp * sn + k * cs; }
  Qh[((size_t)h * NT + n) * HD + lane] = (_Float16)(qr * 0.18033688f);  // 0.125*log2e
  // KF fragment-swizzle: key m=n&63 -> (t, i15); d=lane -> (kk, l4, j)
  int m64 = n & 63, kb = n >> 6;
  int t   = 2 * (m64 >> 5) + ((m64 >> 2) & 1);
  int i15 = 4 * ((m64 >> 3) & 3) + (m64 & 3);
  int kk = lane >> 5, ll4 = (lane >> 3) & 3, jj = lane & 7;
  KF[(size_t)h * NT * HD + (size_t)kb * 4096 +
     (size_t)(((t * 2 + kk) * 64 + ll4 * 16 + i15) * 8 + jj)] = (_Float16)kr;
}

// ---------------- V into fragment-swizzled VF layout ----------------
// VF element (kb, f=t*2+kk, lane=l4*16+l15, j) = V[key=kb*64+kk*32+l4*8+j][d=t*16+l15]
__global__ __launch_bounds__(256) void vtrans_kernel(const _Float16* __restrict__ qkv,
                                                     _Float16* __restrict__ VF) {
  __shared__ _Float16 L[64][72];
  int h = blockIdx.y, n0 = blockIdx.x * 64, kb = blockIdx.x, t0 = threadIdx.x;
#pragma unroll
  for (int i = 0; i < 2; ++i) {
    int cid = t0 + i * 256, r = cid >> 3, c = cid & 7;
    *(half8*)&L[r][c * 8] = *(const half8*)(qkv + (size_t)(n0 + r) * C3 + 2 * CH + h * HD + c * 8);
  }
  __syncthreads();
#pragma unroll
  for (int i = 0; i < 2; ++i) {
    int cid = t0 + i * 256, d = cid >> 3, c = cid & 7;
    half8 v;
#pragma unroll
    for (int jj = 0; jj < 8; ++jj) v[jj] = L[c * 8 + jj][d];
    size_t flat = (size_t)h * NT * HD + (size_t)kb * 4096 +
                  (size_t)((((d >> 4) * 2 + (c >> 2)) * 64 + (c & 3) * 16 + (d & 15)) * 8);
    *(half8*)(VF + flat) = v;
  }
}

// ---------------- flash attention: 2-phase double-buffered gload_lds ----------------
// one block = (head, 128-row Q tile); 4 waves, 32 q-rows each; grid 512.
// Bounded scores (|S|<=8) -> no max tracking. Swapped QK^T -> P in registers.
// Stage(next tile) issued BEFORE compute(current); ONE barrier per tile ->
// the vmcnt drain at the barrier sees loads issued a full compute (~1100 cyc)
// earlier. lsum via MFMA ones-frag. Zero staging VALU / registers.
__global__ __launch_bounds__(256, 2) void attn_kernel(const _Float16* __restrict__ Qh,
                                                      const _Float16* __restrict__ KF,
                                                      const _Float16* __restrict__ VF,
                                                      _Float16* __restrict__ Oh) {
  __shared__ _Float16 KB[2][4096];
  __shared__ _Float16 VB[2][4096];
  const int tid = threadIdx.x, lane = tid & 63, w = tid >> 6;
  const int l15 = lane & 15, l4 = lane >> 4;
  // XCD-aware mapping: 512 blocks, heads {2x,2x+1} pinned to XCD x
  int bid = blockIdx.x;
  int s = bid >> 3;                 // [0,64)
  int h = (bid & 7) * 2 + (s >> 5);
  int n0 = (s & 31) * 128;
  half8 qf[2][2];  // [qb][kk], q rows = n0 + w*32 + qb*16 + l15
#pragma unroll
  for (int qb = 0; qb < 2; ++qb)
#pragma unroll
    for (int kk = 0; kk < 2; ++kk)
      qf[qb][kk] = *(const half8*)(Qh + ((size_t)h * NT + n0 + w * 32 + qb * 16 + l15) * HD + kk * 32 + l4 * 8);
  f32x4 acc[2][4] = {};
  f32x4 acc5[2] = {};              // lsum accumulators (col 0 = row-sum)
  half8 of1 = {};                  // ones B-frag: B[idx=0][k]=1 -> l15==0 lanes
  if (l15 == 0) {
#pragma unroll
    for (int jq = 0; jq < 8; ++jq) of1[jq] = (_Float16)1.0f;
  }
  const _Float16* KFh = KF + (size_t)h * NT * HD + w * 512 + lane * 8;
  const _Float16* VFh = VF + (size_t)h * NT * HD + w * 512 + lane * 8;
  union U { half8 v; half2 p[4]; };
  auto stage = [&](int kb, int buf) {
    size_t g0 = (size_t)kb * 4096;
    GLOAD_LDS16(KFh + g0,        &KB[buf][w * 512]);
    GLOAD_LDS16(KFh + g0 + 2048, &KB[buf][2048 + w * 512]);
    GLOAD_LDS16(VFh + g0,        &VB[buf][w * 512]);
    GLOAD_LDS16(VFh + g0 + 2048, &VB[buf][2048 + w * 512]);
  };
  auto compute = [&](int buf) {
    // QK^T (swapped): sv[qb][t], q = l15
    f32x4 sv[2][4] = {};
    __builtin_amdgcn_s_setprio(1);
#pragma unroll
    for (int t = 0; t < 4; ++t)
#pragma unroll
      for (int kk = 0; kk < 2; ++kk) {
        half8 kf = *(half8*)&KB[buf][(t * 2 + kk) * 512 + lane * 8];
        sv[0][t] = __builtin_amdgcn_mfma_f32_16x16x32_f16(kf, qf[0][kk], sv[0][t], 0, 0, 0);
        sv[1][t] = __builtin_amdgcn_mfma_f32_16x16x32_f16(kf, qf[1][kk], sv[1][t], 0, 0, 0);
      }
    __builtin_amdgcn_s_setprio(0);
    // p = 2^S; pack with v_cvt_pkrtz. pf[kk][j] = e[2kk + (j>>2)][j&3]
    U u[2][2];
#pragma unroll
    for (int qb = 0; qb < 2; ++qb) {
      float e[4][4];
#pragma unroll
      for (int t = 0; t < 4; ++t)
#pragma unroll
        for (int r = 0; r < 4; ++r) e[t][r] = EXP2(sv[qb][t][r]);
      u[qb][0].p[0] = pk_f16(e[0][0], e[0][1]); u[qb][0].p[1] = pk_f16(e[0][2], e[0][3]);
      u[qb][0].p[2] = pk_f16(e[1][0], e[1][1]); u[qb][0].p[3] = pk_f16(e[1][2], e[1][3]);
      u[qb][1].p[0] = pk_f16(e[2][0], e[2][1]); u[qb][1].p[1] = pk_f16(e[2][2], e[2][3]);
      u[qb][1].p[2] = pk_f16(e[3][0], e[3][1]); u[qb][1].p[3] = pk_f16(e[3][2], e[3][3]);
    }
    // O += P @ V ; lsum via ones-frag (no LDS traffic)
    __builtin_amdgcn_s_setprio(1);
#pragma unroll
    for (int t = 0; t < 4; ++t)
#pragma unroll
      for (int kk = 0; kk < 2; ++kk) {
        half8 vf = *(half8*)&VB[buf][(t * 2 + kk) * 512 + lane * 8];
        acc[0][t] = __builtin_amdgcn_mfma_f32_16x16x32_f16(u[0][kk].v, vf, acc[0][t], 0, 0, 0);
        acc[1][t] = __builtin_amdgcn_mfma_f32_16x16x32_f16(u[1][kk].v, vf, acc[1][t], 0, 0, 0);
      }
    acc5[0] = __builtin_amdgcn_mfma_f32_16x16x32_f16(u[0][0].v, of1, acc5[0], 0, 0, 0);
    acc5[0] = __builtin_amdgcn_mfma_f32_16x16x32_f16(u[0][1].v, of1, acc5[0], 0, 0, 0);
    acc5[1] = __builtin_amdgcn_mfma_f32_16x16x32_f16(u[1][0].v, of1, acc5[1], 0, 0, 0);
    acc5[1] = __builtin_amdgcn_mfma_f32_16x16x32_f16(u[1][1].v, of1, acc5[1], 0, 0, 0);
    __builtin_amdgcn_s_setprio(0);
  };
  stage(0, 0);
  __syncthreads();                 // tile 0 staged (vmcnt drain at barrier)
  for (int kb = 0; kb < 64; kb += 2) {
    stage(kb + 1, 1);              // kb+1 <= 63, always valid
    compute(0);                    // tile kb
    __syncthreads();               // buf1 writes drained; buf0 readers done
    if (kb + 2 < 64) stage(kb + 2, 0);
    compute(1);                    // tile kb+1
    __syncthreads();
  }
  // lsum for q-row (qb*16 + l4*4+r) sits in acc5[qb][r] of lane (l4, l15=0)
#pragma unroll
  for (int qb = 0; qb < 2; ++qb) {
    float linv[4];
#pragma unroll
    for (int r = 0; r < 4; ++r) linv[r] = 1.0f / __shfl(acc5[qb][r], lane & 48);
#pragma unroll
    for (int t = 0; t < 4; ++t)
#pragma unroll
      for (int r = 0; r < 4; ++r) {
        int row = n0 + w * 32 + qb * 16 + l4 * 4 + r;
        Oh[(size_t)row * CH + h * HD + t * 16 + l15] = (_Float16)(acc[qb][t][r] * linv[r]);
      }
  }
}

extern "C" void kernel_launch(void* const* d_in, const int* in_sizes, int n_in,
                              void* d_out, int out_size, void* d_ws, size_t ws_size,
                              hipStream_t stream) {
  const float* x      = (const float*)d_in[0];
  const int*   coords = (const int*)d_in[1];
  const float* w_qkv  = (const float*)d_in[2];
  const float* w_out  = (const float*)d_in[3];
  const float* gq     = (const float*)d_in[4];
  const float* gk     = (const float*)d_in[5];
  float* out = (float*)d_out;

  char* ws = (char*)d_ws;
  size_t off = 0;
  auto alloc = [&](size_t bytes) { char* p = ws + off; off += bytes; return p; };
  _Float16* xh   = (_Float16*)alloc((size_t)NT * CH * 2);  // x in f16
  _Float16* wqh  = (_Float16*)alloc((size_t)C3 * CH * 2);  // w_qkv f16
  _Float16* woh  = (_Float16*)alloc((size_t)CH * CH * 2);  // w_out f16
  _Float16* qkvh = (_Float16*)alloc((size_t)NT * C3 * 2);  // qkv f16
  _Float16* Qh   = (_Float16*)alloc((size_t)NT * CH * 2);  // [H][N][64], pre-scaled
  _Float16* KFh  = (_Float16*)alloc((size_t)NT * CH * 2);  // frag-swizzled K
  _Float16* VFh  = (_Float16*)alloc((size_t)NT * CH * 2);  // frag-swizzled V
  _Float16* Oh   = (_Float16*)alloc((size_t)NT * CH * 2);  // attn out [N][C]
  if (off > ws_size) return;  // workspace too small: fail cleanly

  cvt_kernel<<<NT * CH / 4 / 256, 256, 0, stream>>>(x, xh, NT * CH / 4);
  cvt_kernel<<<C3 * CH / 4 / 256, 256, 0, stream>>>(w_qkv, wqh, C3 * CH / 4);
  cvt_kernel<<<CH * CH / 4 / 256, 256, 0, stream>>>(w_out, woh, CH * CH / 4);
  gemm_bt<_Float16><<<dim3(NT / 128, C3 / 128), 256, 0, stream>>>(xh, wqh, qkvh, NT, C3, CH);
  rmsrope_kernel<<<NT * NH / 4, 256, 0, stream>>>(qkvh, coords, gq, gk, Qh, KFh);
  vtrans_kernel<<<dim3(NT / 64, NH), 256, 0, stream>>>(qkvh, VFh);
  attn_kernel<<<NH * (NT / 128), 256, 0, stream>>>(Qh, KFh, VFh, Oh);
  gemm_bt<float><<<dim3(NT / 128, CH / 128), 256, 0, stream>>>(Oh, woh, out, NT, CH, CH);
}